// Round 1
// baseline (879.710 us; speedup 1.0000x reference)
//
#include <hip/hip_runtime.h>
#include <hip/hip_bf16.h>

#define HH 1024
#define II 2048
#define EE 8
#define NTOK 8192
#define NPAIR (NTOK * 2)

typedef __attribute__((ext_vector_type(8))) short bf16x8;
typedef __attribute__((ext_vector_type(4))) float f32x4;

__device__ __forceinline__ ushort f2bf(float f) {
    union { float f; unsigned u; } v; v.f = f;
    unsigned r = v.u + 0x7fffu + ((v.u >> 16) & 1u);
    return (ushort)(r >> 16);
}

// ---------------- gate: logits -> softmax -> top2 -> counts ----------------
__global__ __launch_bounds__(64) void gate_kernel(
    const float* __restrict__ x, const float* __restrict__ Wg,
    int* __restrict__ counts, int* __restrict__ tki, float* __restrict__ tkv)
{
    const int n = blockIdx.x;
    const int lane = threadIdx.x;
    const float* xr = x + (size_t)n * HH;

    float part[EE];
#pragma unroll
    for (int e = 0; e < EE; e++) part[e] = 0.f;

    for (int h = lane; h < HH; h += 64) {
        const float xv = xr[h];
#pragma unroll
        for (int e = 0; e < EE; e++) part[e] += xv * Wg[e * HH + h];
    }
#pragma unroll
    for (int e = 0; e < EE; e++) {
        float v = part[e];
        for (int off = 32; off > 0; off >>= 1) v += __shfl_down(v, off);
        part[e] = v;
    }
    if (lane == 0) {
        float m = part[0];
#pragma unroll
        for (int e = 1; e < EE; e++) m = fmaxf(m, part[e]);
        float p[EE]; float s = 0.f;
#pragma unroll
        for (int e = 0; e < EE; e++) { p[e] = __expf(part[e] - m); s += p[e]; }
        const float inv = 1.f / s;
        int i0 = 0; float v0 = p[0];
#pragma unroll
        for (int e = 1; e < EE; e++) if (p[e] > v0) { v0 = p[e]; i0 = e; }
        int i1 = -1; float v1 = -1.f;
#pragma unroll
        for (int e = 0; e < EE; e++) if (e != i0 && p[e] > v1) { v1 = p[e]; i1 = e; }
        tki[n * 2 + 0] = i0; tkv[n * 2 + 0] = v0 * inv;
        tki[n * 2 + 1] = i1; tkv[n * 2 + 1] = v1 * inv;
        atomicAdd(&counts[i0], 1);
        atomicAdd(&counts[i1], 1);
    }
}

__global__ void offsets_kernel(const int* __restrict__ counts,
                               int* __restrict__ offs, int* __restrict__ cursor)
{
    if (threadIdx.x == 0 && blockIdx.x == 0) {
        int acc = 0;
        for (int e = 0; e < EE; e++) { offs[e] = acc; cursor[e] = acc; acc += counts[e]; }
    }
}

__global__ __launch_bounds__(256) void scatter_kernel(
    const int* __restrict__ tki, const float* __restrict__ tkv,
    int* __restrict__ cursor, int* __restrict__ stok, float* __restrict__ sval)
{
    const int id = blockIdx.x * 256 + threadIdx.x;
    if (id >= NPAIR) return;
    const int e = tki[id];
    const int p = atomicAdd(&cursor[e], 1);
    stok[p] = id >> 1;
    sval[p] = tkv[id];
}

// ---------------- fc1: hid = silu(Xg @ W1[e]^T), bf16 out ----------------
__global__ __launch_bounds__(256) void fc1_kernel(
    const float* __restrict__ x, const float* __restrict__ W1,
    const int* __restrict__ counts, const int* __restrict__ offs,
    const int* __restrict__ stok, ushort* __restrict__ hid)
{
    const int e = blockIdx.z;
    const int cnt = counts[e];
    const int row0 = blockIdx.y * 128;
    if (row0 >= cnt) return;
    const int off = offs[e];
    const int col0 = blockIdx.x * 128;

    __shared__ ushort As[128][32];
    __shared__ ushort Bs[128][32];

    const int tid = threadIdx.x;
    const int lr = tid >> 3;   // 0..31
    const int lc = tid & 7;    // 0..7 (float4 chunk)

    int tok[4]; bool tv[4];
#pragma unroll
    for (int rr = 0; rr < 4; rr++) {
        const int r = rr * 32 + lr;
        tv[rr] = (row0 + r) < cnt;
        tok[rr] = tv[rr] ? stok[off + row0 + r] : 0;
    }

    const int w = tid >> 6, lane = tid & 63;
    const int quad = lane >> 4, l16 = lane & 15;
    const int wm = (w >> 1) * 64, wn = (w & 1) * 64;

    f32x4 acc[4][4];
#pragma unroll
    for (int mi = 0; mi < 4; mi++)
#pragma unroll
        for (int ni = 0; ni < 4; ni++) acc[mi][ni] = f32x4{0.f, 0.f, 0.f, 0.f};

    for (int k0 = 0; k0 < HH; k0 += 32) {
        __syncthreads();
#pragma unroll
        for (int rr = 0; rr < 4; rr++) {
            const int r = rr * 32 + lr;
            float4 f = make_float4(0.f, 0.f, 0.f, 0.f);
            if (tv[rr]) f = *(const float4*)(x + (size_t)tok[rr] * HH + k0 + lc * 4);
            union { ushort h[4]; uint2 u; } pk;
            pk.h[0] = f2bf(f.x); pk.h[1] = f2bf(f.y); pk.h[2] = f2bf(f.z); pk.h[3] = f2bf(f.w);
            *(uint2*)&As[r][lc * 4] = pk.u;
        }
#pragma unroll
        for (int rr = 0; rr < 4; rr++) {
            const int r = rr * 32 + lr;
            const float4 f = *(const float4*)(W1 + ((size_t)e * II + col0 + r) * HH + k0 + lc * 4);
            union { ushort h[4]; uint2 u; } pk;
            pk.h[0] = f2bf(f.x); pk.h[1] = f2bf(f.y); pk.h[2] = f2bf(f.z); pk.h[3] = f2bf(f.w);
            *(uint2*)&Bs[r][lc * 4] = pk.u;
        }
        __syncthreads();

        bf16x8 af[4], bb[4];
#pragma unroll
        for (int mi = 0; mi < 4; mi++) af[mi] = *(const bf16x8*)&As[wm + mi * 16 + l16][quad * 8];
#pragma unroll
        for (int ni = 0; ni < 4; ni++) bb[ni] = *(const bf16x8*)&Bs[wn + ni * 16 + l16][quad * 8];
#pragma unroll
        for (int mi = 0; mi < 4; mi++)
#pragma unroll
            for (int ni = 0; ni < 4; ni++)
                acc[mi][ni] = __builtin_amdgcn_mfma_f32_16x16x32_bf16(af[mi], bb[ni], acc[mi][ni], 0, 0, 0);
    }

    const int cnt_rem = cnt - row0;
#pragma unroll
    for (int mi = 0; mi < 4; mi++) {
#pragma unroll
        for (int j = 0; j < 4; j++) {
            const int r = wm + mi * 16 + quad * 4 + j;
            if (r < cnt_rem) {
                ushort* hrow = hid + (size_t)(off + row0 + r) * II + col0 + wn + l16;
#pragma unroll
                for (int ni = 0; ni < 4; ni++) {
                    const float v = acc[mi][ni][j];
                    const float s = v / (1.f + __expf(-v));
                    hrow[ni * 16] = f2bf(s);
                }
            }
        }
    }
}

// ---------------- fc2: out += val * (hid @ W2[e]^T) ----------------
__global__ __launch_bounds__(256) void fc2_kernel(
    const ushort* __restrict__ hid, const float* __restrict__ W2,
    const int* __restrict__ counts, const int* __restrict__ offs,
    const int* __restrict__ stok, const float* __restrict__ sval,
    float* __restrict__ out)
{
    const int e = blockIdx.z;
    const int cnt = counts[e];
    const int row0 = blockIdx.y * 128;
    if (row0 >= cnt) return;
    const int off = offs[e];
    const int col0 = blockIdx.x * 128;

    __shared__ ushort As[128][32];
    __shared__ ushort Bs[128][32];

    const int tid = threadIdx.x;
    const int ar = tid >> 2;   // 0..63
    const int ac = tid & 3;    // 0..3 (16B chunk)
    const int lr = tid >> 3;   // 0..31
    const int lc = tid & 7;

    const int w = tid >> 6, lane = tid & 63;
    const int quad = lane >> 4, l16 = lane & 15;
    const int wm = (w >> 1) * 64, wn = (w & 1) * 64;

    f32x4 acc[4][4];
#pragma unroll
    for (int mi = 0; mi < 4; mi++)
#pragma unroll
        for (int ni = 0; ni < 4; ni++) acc[mi][ni] = f32x4{0.f, 0.f, 0.f, 0.f};

    for (int k0 = 0; k0 < II; k0 += 32) {
        __syncthreads();
#pragma unroll
        for (int rr = 0; rr < 2; rr++) {
            const int r = rr * 64 + ar;
            uint4 v = make_uint4(0u, 0u, 0u, 0u);
            if (row0 + r < cnt) v = *(const uint4*)(hid + (size_t)(off + row0 + r) * II + k0 + ac * 8);
            *(uint4*)&As[r][ac * 8] = v;
        }
#pragma unroll
        for (int rr = 0; rr < 4; rr++) {
            const int r = rr * 32 + lr;
            const float4 f = *(const float4*)(W2 + ((size_t)e * HH + col0 + r) * II + k0 + lc * 4);
            union { ushort h[4]; uint2 u; } pk;
            pk.h[0] = f2bf(f.x); pk.h[1] = f2bf(f.y); pk.h[2] = f2bf(f.z); pk.h[3] = f2bf(f.w);
            *(uint2*)&Bs[r][lc * 4] = pk.u;
        }
        __syncthreads();

        bf16x8 af[4], bb[4];
#pragma unroll
        for (int mi = 0; mi < 4; mi++) af[mi] = *(const bf16x8*)&As[wm + mi * 16 + l16][quad * 8];
#pragma unroll
        for (int ni = 0; ni < 4; ni++) bb[ni] = *(const bf16x8*)&Bs[wn + ni * 16 + l16][quad * 8];
#pragma unroll
        for (int mi = 0; mi < 4; mi++)
#pragma unroll
            for (int ni = 0; ni < 4; ni++)
                acc[mi][ni] = __builtin_amdgcn_mfma_f32_16x16x32_bf16(af[mi], bb[ni], acc[mi][ni], 0, 0, 0);
    }

    const int cnt_rem = cnt - row0;
#pragma unroll
    for (int mi = 0; mi < 4; mi++) {
#pragma unroll
        for (int j = 0; j < 4; j++) {
            const int r = wm + mi * 16 + quad * 4 + j;
            if (r < cnt_rem) {
                const int p = off + row0 + r;
                const int token = stok[p];
                const float val = sval[p];
                float* orow = out + (size_t)token * HH + col0 + wn + l16;
#pragma unroll
                for (int ni = 0; ni < 4; ni++)
                    atomicAdd(&orow[ni * 16], val * acc[mi][ni][j]);
            }
        }
    }
}

extern "C" void kernel_launch(void* const* d_in, const int* in_sizes, int n_in,
                              void* d_out, int out_size, void* d_ws, size_t ws_size,
                              hipStream_t stream) {
    const float* x  = (const float*)d_in[0];
    const float* Wg = (const float*)d_in[1];
    const float* W1 = (const float*)d_in[2];
    const float* W2 = (const float*)d_in[3];
    float* out = (float*)d_out;

    char* wsb = (char*)d_ws;
    int*    counts = (int*)(wsb + 0);
    int*    cursor = (int*)(wsb + 64);
    int*    offs   = (int*)(wsb + 128);
    int*    tki    = (int*)(wsb + 256);                 // 16384 ints
    float*  tkv    = (float*)(wsb + 256 + 65536);       // 16384 floats
    int*    stok   = (int*)(wsb + 256 + 2 * 65536);     // 16384 ints
    float*  sval   = (float*)(wsb + 256 + 3 * 65536);   // 16384 floats
    ushort* hid    = (ushort*)(wsb + 262400);           // 16384 x 2048 bf16 = 64 MB

    hipMemsetAsync(wsb, 0, 256, stream);
    hipMemsetAsync(d_out, 0, (size_t)out_size * sizeof(float), stream);

    gate_kernel<<<NTOK, 64, 0, stream>>>(x, Wg, counts, tki, tkv);
    offsets_kernel<<<1, 64, 0, stream>>>(counts, offs, cursor);
    scatter_kernel<<<NPAIR / 256, 256, 0, stream>>>(tki, tkv, cursor, stok, sval);
    fc1_kernel<<<dim3(II / 128, NTOK / 128, EE), 256, 0, stream>>>(x, W1, counts, offs, stok, hid);
    fc2_kernel<<<dim3(HH / 128, NTOK / 128, EE), 256, 0, stream>>>(hid, W2, counts, offs, stok, sval, out);
}

// Round 2
// 728.161 us; speedup vs baseline: 1.2081x; 1.2081x over previous
//
#include <hip/hip_runtime.h>
#include <hip/hip_bf16.h>

#define HH 1024
#define II 2048
#define EE 8
#define NTOK 8192
#define NPAIR (NTOK * 2)

typedef __attribute__((ext_vector_type(8))) short bf16x8;
typedef __attribute__((ext_vector_type(4))) float f32x4;
typedef unsigned int u32;

__device__ __forceinline__ ushort f2bf(float f) {
    union { float f; unsigned u; } v; v.f = f;
    unsigned r = v.u + 0x7fffu + ((v.u >> 16) & 1u);
    return (ushort)(r >> 16);
}

__device__ __forceinline__ void gload16(const void* g, void* l) {
    __builtin_amdgcn_global_load_lds((const __attribute__((address_space(1))) u32*)g,
                                     (__attribute__((address_space(3))) u32*)l, 16, 0, 0);
}

// ---------------- fp32 -> bf16 bulk convert ----------------
__global__ __launch_bounds__(256) void cvt_kernel(const float* __restrict__ src,
                                                  ushort* __restrict__ dst, int n4)
{
    const int i = blockIdx.x * 256 + threadIdx.x;
    if (i >= n4) return;
    const float4 f = ((const float4*)src)[i];
    union { ushort h[4]; uint2 u; } pk;
    pk.h[0] = f2bf(f.x); pk.h[1] = f2bf(f.y); pk.h[2] = f2bf(f.z); pk.h[3] = f2bf(f.w);
    ((uint2*)dst)[i] = pk.u;
}

// ---------------- gate: logits -> softmax -> top2 -> counts ----------------
__global__ __launch_bounds__(64) void gate_kernel(
    const float* __restrict__ x, const float* __restrict__ Wg,
    int* __restrict__ counts, int* __restrict__ tki, float* __restrict__ tkv)
{
    const int n = blockIdx.x;
    const int lane = threadIdx.x;
    const float* xr = x + (size_t)n * HH;

    float part[EE];
#pragma unroll
    for (int e = 0; e < EE; e++) part[e] = 0.f;

    for (int h = lane; h < HH; h += 64) {
        const float xv = xr[h];
#pragma unroll
        for (int e = 0; e < EE; e++) part[e] += xv * Wg[e * HH + h];
    }
#pragma unroll
    for (int e = 0; e < EE; e++) {
        float v = part[e];
        for (int off = 32; off > 0; off >>= 1) v += __shfl_down(v, off);
        part[e] = v;
    }
    if (lane == 0) {
        float m = part[0];
#pragma unroll
        for (int e = 1; e < EE; e++) m = fmaxf(m, part[e]);
        float p[EE]; float s = 0.f;
#pragma unroll
        for (int e = 0; e < EE; e++) { p[e] = __expf(part[e] - m); s += p[e]; }
        const float inv = 1.f / s;
        int i0 = 0; float v0 = p[0];
#pragma unroll
        for (int e = 1; e < EE; e++) if (p[e] > v0) { v0 = p[e]; i0 = e; }
        int i1 = -1; float v1 = -1.f;
#pragma unroll
        for (int e = 0; e < EE; e++) if (e != i0 && p[e] > v1) { v1 = p[e]; i1 = e; }
        tki[n * 2 + 0] = i0; tkv[n * 2 + 0] = v0 * inv;
        tki[n * 2 + 1] = i1; tkv[n * 2 + 1] = v1 * inv;
        atomicAdd(&counts[i0], 1);
        atomicAdd(&counts[i1], 1);
    }
}

__global__ void offsets_kernel(const int* __restrict__ counts,
                               int* __restrict__ offs, int* __restrict__ cursor)
{
    if (threadIdx.x == 0 && blockIdx.x == 0) {
        int acc = 0;
        for (int e = 0; e < EE; e++) { offs[e] = acc; cursor[e] = acc; acc += counts[e]; }
    }
}

__global__ __launch_bounds__(256) void scatter_kernel(
    const int* __restrict__ tki, const float* __restrict__ tkv,
    int* __restrict__ cursor, int* __restrict__ stok, float* __restrict__ sval)
{
    const int id = blockIdx.x * 256 + threadIdx.x;
    if (id >= NPAIR) return;
    const int e = tki[id];
    const int p = atomicAdd(&cursor[e], 1);
    stok[p] = id >> 1;
    sval[p] = tkv[id];
}

// ---------------- fc1: hid = silu(Xg @ W1[e]^T), bf16 out ----------------
// 128x128 tile, BK=64, 4 waves, 4x4 16x16x32 MFMA per wave.
template <bool PRE>
__global__ __launch_bounds__(256) void fc1_kernel(
    const float* __restrict__ x, const ushort* __restrict__ xb,
    const float* __restrict__ W1, const ushort* __restrict__ W1b,
    const int* __restrict__ counts, const int* __restrict__ offs,
    const int* __restrict__ stok, ushort* __restrict__ hid)
{
    const int e = blockIdx.z;
    const int cnt = counts[e];
    const int row0 = blockIdx.y * 128;
    if (row0 >= cnt) return;
    const int off = offs[e];
    const int col0 = blockIdx.x * 128;

    __shared__ __align__(16) ushort As[128 * 64];
    __shared__ __align__(16) ushort Bs[128 * 64];

    const int tid = threadIdx.x;
    const int w = tid >> 6, lane = tid & 63;
    const int quad = lane >> 4, l16 = lane & 15;
    const int wm = (w >> 1) * 64, wn = (w & 1) * 64;

    f32x4 acc[4][4];
#pragma unroll
    for (int mi = 0; mi < 4; mi++)
#pragma unroll
        for (int ni = 0; ni < 4; ni++) acc[mi][ni] = f32x4{0.f, 0.f, 0.f, 0.f};

    // async staging geometry: 8 rows / instruction / wave
    const int sub = lane >> 3;     // 0..7  (row within 8-row group)
    const int chk = lane & 7;      // 0..7  (16B chunk within 128B row)
    int tokA[4];
    // fallback geometry
    const int fr = tid >> 1;             // 0..127
    const int fc = (tid & 1) * 32;       // 0 or 32
    int tokF = 0;
    if (PRE) {
#pragma unroll
        for (int i = 0; i < 4; i++) {
            int r = row0 + (w * 4 + i) * 8 + sub;
            if (r >= cnt) r = cnt - 1;
            tokA[i] = stok[off + r];
        }
    } else {
        int r = row0 + fr;
        if (r >= cnt) r = cnt - 1;
        tokF = stok[off + r];
    }

    for (int k0 = 0; k0 < HH; k0 += 64) {
        __syncthreads();
        if (PRE) {
#pragma unroll
            for (int i = 0; i < 4; i++) {
                const ushort* gA = xb + (size_t)tokA[i] * HH + k0 + chk * 8;
                gload16(gA, &As[(w * 4 + i) * 512]);
                const ushort* gB = W1b + ((size_t)e * II + col0 + (w * 4 + i) * 8 + sub) * HH + k0 + chk * 8;
                gload16(gB, &Bs[(w * 4 + i) * 512]);
            }
        } else {
#pragma unroll
            for (int c = 0; c < 32; c += 4) {
                const float4 f = *(const float4*)(x + (size_t)tokF * HH + k0 + fc + c);
                union { ushort h[4]; uint2 u; } pk;
                pk.h[0] = f2bf(f.x); pk.h[1] = f2bf(f.y); pk.h[2] = f2bf(f.z); pk.h[3] = f2bf(f.w);
                *(uint2*)&As[fr * 64 + fc + c] = pk.u;
                const float4 g = *(const float4*)(W1 + ((size_t)e * II + col0 + fr) * HH + k0 + fc + c);
                pk.h[0] = f2bf(g.x); pk.h[1] = f2bf(g.y); pk.h[2] = f2bf(g.z); pk.h[3] = f2bf(g.w);
                *(uint2*)&Bs[fr * 64 + fc + c] = pk.u;
            }
        }
        __syncthreads();

#pragma unroll
        for (int kk = 0; kk < 2; kk++) {
            bf16x8 af[4], bb[4];
#pragma unroll
            for (int mi = 0; mi < 4; mi++)
                af[mi] = *(const bf16x8*)&As[(wm + mi * 16 + l16) * 64 + kk * 32 + quad * 8];
#pragma unroll
            for (int ni = 0; ni < 4; ni++)
                bb[ni] = *(const bf16x8*)&Bs[(wn + ni * 16 + l16) * 64 + kk * 32 + quad * 8];
#pragma unroll
            for (int mi = 0; mi < 4; mi++)
#pragma unroll
                for (int ni = 0; ni < 4; ni++)
                    acc[mi][ni] = __builtin_amdgcn_mfma_f32_16x16x32_bf16(af[mi], bb[ni], acc[mi][ni], 0, 0, 0);
        }
    }

    const int cnt_rem = cnt - row0;
#pragma unroll
    for (int mi = 0; mi < 4; mi++) {
#pragma unroll
        for (int j = 0; j < 4; j++) {
            const int r = wm + mi * 16 + quad * 4 + j;
            if (r < cnt_rem) {
                ushort* hrow = hid + (size_t)(off + row0 + r) * II + col0 + wn + l16;
#pragma unroll
                for (int ni = 0; ni < 4; ni++) {
                    const float v = acc[mi][ni][j];
                    const float s = v / (1.f + __expf(-v));
                    hrow[ni * 16] = f2bf(s);
                }
            }
        }
    }
}

// ---------------- fc2: out += val * (hid @ W2[e]^T) ----------------
template <bool PRE>
__global__ __launch_bounds__(256) void fc2_kernel(
    const ushort* __restrict__ hid,
    const float* __restrict__ W2, const ushort* __restrict__ W2b,
    const int* __restrict__ counts, const int* __restrict__ offs,
    const int* __restrict__ stok, const float* __restrict__ sval,
    float* __restrict__ out)
{
    const int e = blockIdx.z;
    const int cnt = counts[e];
    const int row0 = blockIdx.y * 128;
    if (row0 >= cnt) return;
    const int off = offs[e];
    const int col0 = blockIdx.x * 128;

    __shared__ __align__(16) ushort As[128 * 64];
    __shared__ __align__(16) ushort Bs[128 * 64];

    const int tid = threadIdx.x;
    const int w = tid >> 6, lane = tid & 63;
    const int quad = lane >> 4, l16 = lane & 15;
    const int wm = (w >> 1) * 64, wn = (w & 1) * 64;

    f32x4 acc[4][4];
#pragma unroll
    for (int mi = 0; mi < 4; mi++)
#pragma unroll
        for (int ni = 0; ni < 4; ni++) acc[mi][ni] = f32x4{0.f, 0.f, 0.f, 0.f};

    const int sub = lane >> 3;
    const int chk = lane & 7;
    size_t slotA[4];
#pragma unroll
    for (int i = 0; i < 4; i++) {
        int s = off + row0 + (w * 4 + i) * 8 + sub;
        if (s > NPAIR - 1) s = NPAIR - 1;
        slotA[i] = (size_t)s;
    }
    const int fr = tid >> 1;
    const int fc = (tid & 1) * 32;

    for (int k0 = 0; k0 < II; k0 += 64) {
        __syncthreads();
#pragma unroll
        for (int i = 0; i < 4; i++) {
            const ushort* gA = hid + slotA[i] * II + k0 + chk * 8;
            gload16(gA, &As[(w * 4 + i) * 512]);
        }
        if (PRE) {
#pragma unroll
            for (int i = 0; i < 4; i++) {
                const ushort* gB = W2b + ((size_t)e * HH + col0 + (w * 4 + i) * 8 + sub) * II + k0 + chk * 8;
                gload16(gB, &Bs[(w * 4 + i) * 512]);
            }
        } else {
#pragma unroll
            for (int c = 0; c < 32; c += 4) {
                const float4 g = *(const float4*)(W2 + ((size_t)e * HH + col0 + fr) * II + k0 + fc + c);
                union { ushort h[4]; uint2 u; } pk;
                pk.h[0] = f2bf(g.x); pk.h[1] = f2bf(g.y); pk.h[2] = f2bf(g.z); pk.h[3] = f2bf(g.w);
                *(uint2*)&Bs[fr * 64 + fc + c] = pk.u;
            }
        }
        __syncthreads();

#pragma unroll
        for (int kk = 0; kk < 2; kk++) {
            bf16x8 af[4], bb[4];
#pragma unroll
            for (int mi = 0; mi < 4; mi++)
                af[mi] = *(const bf16x8*)&As[(wm + mi * 16 + l16) * 64 + kk * 32 + quad * 8];
#pragma unroll
            for (int ni = 0; ni < 4; ni++)
                bb[ni] = *(const bf16x8*)&Bs[(wn + ni * 16 + l16) * 64 + kk * 32 + quad * 8];
#pragma unroll
            for (int mi = 0; mi < 4; mi++)
#pragma unroll
                for (int ni = 0; ni < 4; ni++)
                    acc[mi][ni] = __builtin_amdgcn_mfma_f32_16x16x32_bf16(af[mi], bb[ni], acc[mi][ni], 0, 0, 0);
        }
    }

    const int cnt_rem = cnt - row0;
#pragma unroll
    for (int mi = 0; mi < 4; mi++) {
#pragma unroll
        for (int j = 0; j < 4; j++) {
            const int r = wm + mi * 16 + quad * 4 + j;
            if (r < cnt_rem) {
                const int p = off + row0 + r;
                const int token = stok[p];
                const float val = sval[p];
                float* orow = out + (size_t)token * HH + col0 + wn + l16;
#pragma unroll
                for (int ni = 0; ni < 4; ni++)
                    atomicAdd(&orow[ni * 16], val * acc[mi][ni][j]);
            }
        }
    }
}

extern "C" void kernel_launch(void* const* d_in, const int* in_sizes, int n_in,
                              void* d_out, int out_size, void* d_ws, size_t ws_size,
                              hipStream_t stream) {
    const float* x  = (const float*)d_in[0];
    const float* Wg = (const float*)d_in[1];
    const float* W1 = (const float*)d_in[2];
    const float* W2 = (const float*)d_in[3];
    float* out = (float*)d_out;

    char* wsb = (char*)d_ws;
    int*    counts = (int*)(wsb + 0);
    int*    cursor = (int*)(wsb + 64);
    int*    offs   = (int*)(wsb + 128);
    int*    tki    = (int*)(wsb + 256);
    float*  tkv    = (float*)(wsb + 256 + 65536);
    int*    stok   = (int*)(wsb + 256 + 2 * 65536);
    float*  sval   = (float*)(wsb + 256 + 3 * 65536);
    ushort* hid    = (ushort*)(wsb + 262400);                        // 64 MB
    ushort* W1b    = (ushort*)(wsb + 262400 + 67108864ull);          // 32 MB
    ushort* W2b    = (ushort*)(wsb + 262400 + 100663296ull);         // 32 MB
    ushort* xb     = (ushort*)(wsb + 262400 + 134217728ull);         // 16 MB
    const size_t REQ = 262400ull + 134217728ull + 16777216ull;       // ~144.3 MB
    const bool pre = ws_size >= REQ;

    hipMemsetAsync(wsb, 0, 256, stream);
    hipMemsetAsync(d_out, 0, (size_t)out_size * sizeof(float), stream);

    gate_kernel<<<NTOK, 64, 0, stream>>>(x, Wg, counts, tki, tkv);
    offsets_kernel<<<1, 64, 0, stream>>>(counts, offs, cursor);
    scatter_kernel<<<NPAIR / 256, 256, 0, stream>>>(tki, tkv, cursor, stok, sval);

    if (pre) {
        cvt_kernel<<<(NTOK * HH / 4 + 255) / 256, 256, 0, stream>>>(x, xb, NTOK * HH / 4);
        cvt_kernel<<<(EE * II * HH / 4 + 255) / 256, 256, 0, stream>>>(W1, W1b, EE * II * HH / 4);
        cvt_kernel<<<(EE * HH * II / 4 + 255) / 256, 256, 0, stream>>>(W2, W2b, EE * HH * II / 4);
        fc1_kernel<true><<<dim3(II / 128, NPAIR / 128, EE), 256, 0, stream>>>(x, xb, W1, W1b, counts, offs, stok, hid);
        fc2_kernel<true><<<dim3(HH / 128, NPAIR / 128, EE), 256, 0, stream>>>(hid, W2, W2b, counts, offs, stok, sval, out);
    } else {
        fc1_kernel<false><<<dim3(II / 128, NPAIR / 128, EE), 256, 0, stream>>>(x, xb, W1, W1b, counts, offs, stok, hid);
        fc2_kernel<false><<<dim3(HH / 128, NPAIR / 128, EE), 256, 0, stream>>>(hid, W2, W2b, counts, offs, stok, sval, out);
    }
}

// Round 3
// 487.567 us; speedup vs baseline: 1.8043x; 1.4935x over previous
//
#include <hip/hip_runtime.h>
#include <hip/hip_bf16.h>

#define HH 1024
#define II 2048
#define EE 8
#define NTOK 8192
#define NPAIR (NTOK * 2)

typedef __attribute__((ext_vector_type(8))) short bf16x8;
typedef __attribute__((ext_vector_type(4))) float f32x4;
typedef unsigned int u32;

__device__ __forceinline__ ushort f2bf(float f) {
    union { float f; unsigned u; } v; v.f = f;
    unsigned r = v.u + 0x7fffu + ((v.u >> 16) & 1u);
    return (ushort)(r >> 16);
}

__device__ __forceinline__ void gload16(const void* g, void* l) {
    __builtin_amdgcn_global_load_lds((const __attribute__((address_space(1))) u32*)g,
                                     (__attribute__((address_space(3))) u32*)l, 16, 0, 0);
}

// ---------------- fp32 -> bf16 bulk convert ----------------
__global__ __launch_bounds__(256) void cvt_kernel(const float* __restrict__ src,
                                                  ushort* __restrict__ dst, int n4)
{
    const int i = blockIdx.x * 256 + threadIdx.x;
    if (i >= n4) return;
    const float4 f = ((const float4*)src)[i];
    union { ushort h[4]; uint2 u; } pk;
    pk.h[0] = f2bf(f.x); pk.h[1] = f2bf(f.y); pk.h[2] = f2bf(f.z); pk.h[3] = f2bf(f.w);
    ((uint2*)dst)[i] = pk.u;
}

// ---------------- gate: wave-per-token, LDS histogram, 8 atomics/block ----------------
// 256 blocks x 256 threads; each wave handles 8 tokens.
__global__ __launch_bounds__(256) void gate_kernel(
    const float* __restrict__ x, const float* __restrict__ Wg,
    int* __restrict__ counts, int* __restrict__ tki, float* __restrict__ tkv)
{
    __shared__ int hist[EE];
    const int tid = threadIdx.x;
    if (tid < EE) hist[tid] = 0;
    __syncthreads();

    const int w = tid >> 6, lane = tid & 63;

#pragma unroll 1
    for (int t = 0; t < 8; t++) {
        const int n = blockIdx.x * 32 + w * 8 + t;
        const float* xr = x + (size_t)n * HH;
        float4 xv[4];
#pragma unroll
        for (int c = 0; c < 4; c++) xv[c] = *(const float4*)(xr + c * 256 + lane * 4);

        float dot[EE];
#pragma unroll
        for (int e = 0; e < EE; e++) {
            float s = 0.f;
#pragma unroll
            for (int c = 0; c < 4; c++) {
                const float4 wv = *(const float4*)(Wg + e * HH + c * 256 + lane * 4);
                s += xv[c].x * wv.x + xv[c].y * wv.y + xv[c].z * wv.z + xv[c].w * wv.w;
            }
            for (int off = 32; off > 0; off >>= 1) s += __shfl_down(s, off);
            dot[e] = s;
        }
        if (lane == 0) {
            float m = dot[0];
#pragma unroll
            for (int e = 1; e < EE; e++) m = fmaxf(m, dot[e]);
            float p[EE]; float sum = 0.f;
#pragma unroll
            for (int e = 0; e < EE; e++) { p[e] = __expf(dot[e] - m); sum += p[e]; }
            const float inv = 1.f / sum;
            int i0 = 0; float v0 = p[0];
#pragma unroll
            for (int e = 1; e < EE; e++) if (p[e] > v0) { v0 = p[e]; i0 = e; }
            int i1 = -1; float v1 = -1.f;
#pragma unroll
            for (int e = 0; e < EE; e++) if (e != i0 && p[e] > v1) { v1 = p[e]; i1 = e; }
            tki[n * 2 + 0] = i0; tkv[n * 2 + 0] = v0 * inv;
            tki[n * 2 + 1] = i1; tkv[n * 2 + 1] = v1 * inv;
            atomicAdd(&hist[i0], 1);
            atomicAdd(&hist[i1], 1);
        }
    }
    __syncthreads();
    if (tid < EE) atomicAdd(&counts[tid], hist[tid]);
}

__global__ void offsets_kernel(const int* __restrict__ counts,
                               int* __restrict__ offs, int* __restrict__ cursor)
{
    if (threadIdx.x == 0 && blockIdx.x == 0) {
        int acc = 0;
        for (int e = 0; e < EE; e++) { offs[e] = acc; cursor[e] = acc; acc += counts[e]; }
    }
}

// ---------------- scatter: LDS histogram + one base-reservation atomic per expert/block ----
__global__ __launch_bounds__(256) void scatter_kernel(
    const int* __restrict__ tki, const float* __restrict__ tkv,
    int* __restrict__ cursor, int* __restrict__ stok, float* __restrict__ sval)
{
    __shared__ int hist[EE];
    __shared__ int base[EE];
    const int tid = threadIdx.x;
    const int id = blockIdx.x * 256 + tid;
    if (tid < EE) hist[tid] = 0;
    __syncthreads();
    const int e = tki[id];
    const int loc = atomicAdd(&hist[e], 1);
    __syncthreads();
    if (tid < EE) base[tid] = atomicAdd(&cursor[tid], hist[tid]);
    __syncthreads();
    const int p = base[e] + loc;
    stok[p] = id >> 1;
    sval[p] = tkv[id];
}

// ---------------- fc1: hid = silu(Xg @ W1[e]^T), bf16 out ----------------
// 128x128 tile, BK=64, 4 waves, 4x4 16x16x32 MFMA per wave.
template <bool PRE>
__global__ __launch_bounds__(256) void fc1_kernel(
    const float* __restrict__ x, const ushort* __restrict__ xb,
    const float* __restrict__ W1, const ushort* __restrict__ W1b,
    const int* __restrict__ counts, const int* __restrict__ offs,
    const int* __restrict__ stok, ushort* __restrict__ hid)
{
    const int e = blockIdx.z;
    const int cnt = counts[e];
    const int row0 = blockIdx.y * 128;
    if (row0 >= cnt) return;
    const int off = offs[e];
    const int col0 = blockIdx.x * 128;

    __shared__ __align__(16) ushort As[128 * 64];
    __shared__ __align__(16) ushort Bs[128 * 64];

    const int tid = threadIdx.x;
    const int w = tid >> 6, lane = tid & 63;
    const int quad = lane >> 4, l16 = lane & 15;
    const int wm = (w >> 1) * 64, wn = (w & 1) * 64;

    f32x4 acc[4][4];
#pragma unroll
    for (int mi = 0; mi < 4; mi++)
#pragma unroll
        for (int ni = 0; ni < 4; ni++) acc[mi][ni] = f32x4{0.f, 0.f, 0.f, 0.f};

    const int sub = lane >> 3;     // 0..7
    const int chk = lane & 7;      // 0..7
    int tokA[4];
    const int fr = tid >> 1;
    const int fc = (tid & 1) * 32;
    int tokF = 0;
    if (PRE) {
#pragma unroll
        for (int i = 0; i < 4; i++) {
            int r = row0 + (w * 4 + i) * 8 + sub;
            if (r >= cnt) r = cnt - 1;
            tokA[i] = stok[off + r];
        }
    } else {
        int r = row0 + fr;
        if (r >= cnt) r = cnt - 1;
        tokF = stok[off + r];
    }

    for (int k0 = 0; k0 < HH; k0 += 64) {
        __syncthreads();
        if (PRE) {
#pragma unroll
            for (int i = 0; i < 4; i++) {
                const ushort* gA = xb + (size_t)tokA[i] * HH + k0 + chk * 8;
                gload16(gA, &As[(w * 4 + i) * 512]);
                const ushort* gB = W1b + ((size_t)e * II + col0 + (w * 4 + i) * 8 + sub) * HH + k0 + chk * 8;
                gload16(gB, &Bs[(w * 4 + i) * 512]);
            }
        } else {
#pragma unroll
            for (int c = 0; c < 32; c += 4) {
                const float4 f = *(const float4*)(x + (size_t)tokF * HH + k0 + fc + c);
                union { ushort h[4]; uint2 u; } pk;
                pk.h[0] = f2bf(f.x); pk.h[1] = f2bf(f.y); pk.h[2] = f2bf(f.z); pk.h[3] = f2bf(f.w);
                *(uint2*)&As[fr * 64 + fc + c] = pk.u;
                const float4 g = *(const float4*)(W1 + ((size_t)e * II + col0 + fr) * HH + k0 + fc + c);
                pk.h[0] = f2bf(g.x); pk.h[1] = f2bf(g.y); pk.h[2] = f2bf(g.z); pk.h[3] = f2bf(g.w);
                *(uint2*)&Bs[fr * 64 + fc + c] = pk.u;
            }
        }
        __syncthreads();

#pragma unroll
        for (int kk = 0; kk < 2; kk++) {
            bf16x8 af[4], bb[4];
#pragma unroll
            for (int mi = 0; mi < 4; mi++)
                af[mi] = *(const bf16x8*)&As[(wm + mi * 16 + l16) * 64 + kk * 32 + quad * 8];
#pragma unroll
            for (int ni = 0; ni < 4; ni++)
                bb[ni] = *(const bf16x8*)&Bs[(wn + ni * 16 + l16) * 64 + kk * 32 + quad * 8];
#pragma unroll
            for (int mi = 0; mi < 4; mi++)
#pragma unroll
                for (int ni = 0; ni < 4; ni++)
                    acc[mi][ni] = __builtin_amdgcn_mfma_f32_16x16x32_bf16(af[mi], bb[ni], acc[mi][ni], 0, 0, 0);
        }
    }

    const int cnt_rem = cnt - row0;
#pragma unroll
    for (int mi = 0; mi < 4; mi++) {
#pragma unroll
        for (int j = 0; j < 4; j++) {
            const int r = wm + mi * 16 + quad * 4 + j;
            if (r < cnt_rem) {
                ushort* hrow = hid + (size_t)(off + row0 + r) * II + col0 + wn + l16;
#pragma unroll
                for (int ni = 0; ni < 4; ni++) {
                    const float v = acc[mi][ni][j];
                    const float s = v / (1.f + __expf(-v));
                    hrow[ni * 16] = f2bf(s);
                }
            }
        }
    }
}

// ---------------- fc2: out += val * (hid @ W2[e]^T) ----------------
template <bool PRE>
__global__ __launch_bounds__(256) void fc2_kernel(
    const ushort* __restrict__ hid,
    const float* __restrict__ W2, const ushort* __restrict__ W2b,
    const int* __restrict__ counts, const int* __restrict__ offs,
    const int* __restrict__ stok, const float* __restrict__ sval,
    float* __restrict__ out)
{
    const int e = blockIdx.z;
    const int cnt = counts[e];
    const int row0 = blockIdx.y * 128;
    if (row0 >= cnt) return;
    const int off = offs[e];
    const int col0 = blockIdx.x * 128;

    __shared__ __align__(16) ushort As[128 * 64];
    __shared__ __align__(16) ushort Bs[128 * 64];

    const int tid = threadIdx.x;
    const int w = tid >> 6, lane = tid & 63;
    const int quad = lane >> 4, l16 = lane & 15;
    const int wm = (w >> 1) * 64, wn = (w & 1) * 64;

    f32x4 acc[4][4];
#pragma unroll
    for (int mi = 0; mi < 4; mi++)
#pragma unroll
        for (int ni = 0; ni < 4; ni++) acc[mi][ni] = f32x4{0.f, 0.f, 0.f, 0.f};

    const int sub = lane >> 3;
    const int chk = lane & 7;
    size_t slotA[4];
#pragma unroll
    for (int i = 0; i < 4; i++) {
        int s = off + row0 + (w * 4 + i) * 8 + sub;
        if (s > NPAIR - 1) s = NPAIR - 1;
        slotA[i] = (size_t)s;
    }
    const int fr = tid >> 1;
    const int fc = (tid & 1) * 32;

    for (int k0 = 0; k0 < II; k0 += 64) {
        __syncthreads();
#pragma unroll
        for (int i = 0; i < 4; i++) {
            const ushort* gA = hid + slotA[i] * II + k0 + chk * 8;
            gload16(gA, &As[(w * 4 + i) * 512]);
        }
        if (PRE) {
#pragma unroll
            for (int i = 0; i < 4; i++) {
                const ushort* gB = W2b + ((size_t)e * HH + col0 + (w * 4 + i) * 8 + sub) * II + k0 + chk * 8;
                gload16(gB, &Bs[(w * 4 + i) * 512]);
            }
        } else {
#pragma unroll
            for (int c = 0; c < 32; c += 4) {
                const float4 g = *(const float4*)(W2 + ((size_t)e * HH + col0 + fr) * II + k0 + fc + c);
                union { ushort h[4]; uint2 u; } pk;
                pk.h[0] = f2bf(g.x); pk.h[1] = f2bf(g.y); pk.h[2] = f2bf(g.z); pk.h[3] = f2bf(g.w);
                *(uint2*)&Bs[fr * 64 + fc + c] = pk.u;
            }
        }
        __syncthreads();

#pragma unroll
        for (int kk = 0; kk < 2; kk++) {
            bf16x8 af[4], bb[4];
#pragma unroll
            for (int mi = 0; mi < 4; mi++)
                af[mi] = *(const bf16x8*)&As[(wm + mi * 16 + l16) * 64 + kk * 32 + quad * 8];
#pragma unroll
            for (int ni = 0; ni < 4; ni++)
                bb[ni] = *(const bf16x8*)&Bs[(wn + ni * 16 + l16) * 64 + kk * 32 + quad * 8];
#pragma unroll
            for (int mi = 0; mi < 4; mi++)
#pragma unroll
                for (int ni = 0; ni < 4; ni++)
                    acc[mi][ni] = __builtin_amdgcn_mfma_f32_16x16x32_bf16(af[mi], bb[ni], acc[mi][ni], 0, 0, 0);
        }
    }

    const int cnt_rem = cnt - row0;
#pragma unroll
    for (int mi = 0; mi < 4; mi++) {
#pragma unroll
        for (int j = 0; j < 4; j++) {
            const int r = wm + mi * 16 + quad * 4 + j;
            if (r < cnt_rem) {
                const int p = off + row0 + r;
                const int token = stok[p];
                const float val = sval[p];
                float* orow = out + (size_t)token * HH + col0 + wn + l16;
#pragma unroll
                for (int ni = 0; ni < 4; ni++)
                    atomicAdd(&orow[ni * 16], val * acc[mi][ni][j]);
            }
        }
    }
}

extern "C" void kernel_launch(void* const* d_in, const int* in_sizes, int n_in,
                              void* d_out, int out_size, void* d_ws, size_t ws_size,
                              hipStream_t stream) {
    const float* x  = (const float*)d_in[0];
    const float* Wg = (const float*)d_in[1];
    const float* W1 = (const float*)d_in[2];
    const float* W2 = (const float*)d_in[3];
    float* out = (float*)d_out;

    char* wsb = (char*)d_ws;
    int*    counts = (int*)(wsb + 0);
    int*    cursor = (int*)(wsb + 64);
    int*    offs   = (int*)(wsb + 128);
    int*    tki    = (int*)(wsb + 256);
    float*  tkv    = (float*)(wsb + 256 + 65536);
    int*    stok   = (int*)(wsb + 256 + 2 * 65536);
    float*  sval   = (float*)(wsb + 256 + 3 * 65536);
    ushort* hid    = (ushort*)(wsb + 262400);                        // 64 MB
    ushort* W1b    = (ushort*)(wsb + 262400 + 67108864ull);          // 32 MB
    ushort* W2b    = (ushort*)(wsb + 262400 + 100663296ull);         // 32 MB
    ushort* xb     = (ushort*)(wsb + 262400 + 134217728ull);         // 16 MB
    const size_t REQ = 262400ull + 134217728ull + 16777216ull;       // ~144.3 MB
    const bool pre = ws_size >= REQ;

    hipMemsetAsync(wsb, 0, 256, stream);
    hipMemsetAsync(d_out, 0, (size_t)out_size * sizeof(float), stream);

    gate_kernel<<<NTOK / 32, 256, 0, stream>>>(x, Wg, counts, tki, tkv);
    offsets_kernel<<<1, 64, 0, stream>>>(counts, offs, cursor);
    scatter_kernel<<<NPAIR / 256, 256, 0, stream>>>(tki, tkv, cursor, stok, sval);

    if (pre) {
        cvt_kernel<<<(NTOK * HH / 4 + 255) / 256, 256, 0, stream>>>(x, xb, NTOK * HH / 4);
        cvt_kernel<<<(EE * II * HH / 4 + 255) / 256, 256, 0, stream>>>(W1, W1b, EE * II * HH / 4);
        cvt_kernel<<<(EE * HH * II / 4 + 255) / 256, 256, 0, stream>>>(W2, W2b, EE * HH * II / 4);
        fc1_kernel<true><<<dim3(II / 128, NPAIR / 128, EE), 256, 0, stream>>>(x, xb, W1, W1b, counts, offs, stok, hid);
        fc2_kernel<true><<<dim3(HH / 128, NPAIR / 128, EE), 256, 0, stream>>>(hid, W2, W2b, counts, offs, stok, sval, out);
    } else {
        fc1_kernel<false><<<dim3(II / 128, NPAIR / 128, EE), 256, 0, stream>>>(x, xb, W1, W1b, counts, offs, stok, hid);
        fc2_kernel<false><<<dim3(HH / 128, NPAIR / 128, EE), 256, 0, stream>>>(hid, W2, W2b, counts, offs, stok, sval, out);
    }
}

// Round 4
// 479.716 us; speedup vs baseline: 1.8338x; 1.0164x over previous
//
#include <hip/hip_runtime.h>
#include <hip/hip_bf16.h>

#define HH 1024
#define II 2048
#define EE 8
#define NTOK 8192
#define NPAIR (NTOK * 2)

typedef __attribute__((ext_vector_type(8))) short bf16x8;
typedef __attribute__((ext_vector_type(4))) float f32x4;
typedef unsigned int u32;

__device__ __forceinline__ ushort f2bf(float f) {
    union { float f; unsigned u; } v; v.f = f;
    unsigned r = v.u + 0x7fffu + ((v.u >> 16) & 1u);
    return (ushort)(r >> 16);
}

__device__ __forceinline__ void gload16(const void* g, void* l) {
    __builtin_amdgcn_global_load_lds((const __attribute__((address_space(1))) u32*)g,
                                     (__attribute__((address_space(3))) u32*)l, 16, 0, 0);
}

// ---------------- fp32 -> bf16 convert for W1 and W2 (one dispatch) ----------------
__global__ __launch_bounds__(256) void cvtw_kernel(
    const float* __restrict__ W1, const float* __restrict__ W2,
    ushort* __restrict__ W1b, ushort* __restrict__ W2b)
{
    const int N1 = EE * II * HH / 4;
    const int i = blockIdx.x * 256 + threadIdx.x;
    const float4 f = (i < N1) ? ((const float4*)W1)[i] : ((const float4*)W2)[i - N1];
    union { ushort h[4]; uint2 u; } pk;
    pk.h[0] = f2bf(f.x); pk.h[1] = f2bf(f.y); pk.h[2] = f2bf(f.z); pk.h[3] = f2bf(f.w);
    if (i < N1) ((uint2*)W1b)[i] = pk.u;
    else        ((uint2*)W2b)[i - N1] = pk.u;
}

// ---------------- gate: wave-per-token + emits xb (bf16 x) ----------------
__global__ __launch_bounds__(256) void gate_kernel(
    const float* __restrict__ x, const float* __restrict__ Wg,
    int* __restrict__ counts, int* __restrict__ tki, float* __restrict__ tkv,
    ushort* __restrict__ xb)
{
    __shared__ int hist[EE];
    const int tid = threadIdx.x;
    if (tid < EE) hist[tid] = 0;
    __syncthreads();

    const int w = tid >> 6, lane = tid & 63;

#pragma unroll 1
    for (int t = 0; t < 8; t++) {
        const int n = blockIdx.x * 32 + w * 8 + t;
        const float* xr = x + (size_t)n * HH;
        float4 xv[4];
#pragma unroll
        for (int c = 0; c < 4; c++) xv[c] = *(const float4*)(xr + c * 256 + lane * 4);

        // emit bf16 copy of x
#pragma unroll
        for (int c = 0; c < 4; c++) {
            union { ushort h[4]; uint2 u; } pk;
            pk.h[0] = f2bf(xv[c].x); pk.h[1] = f2bf(xv[c].y);
            pk.h[2] = f2bf(xv[c].z); pk.h[3] = f2bf(xv[c].w);
            *(uint2*)(xb + (size_t)n * HH + c * 256 + lane * 4) = pk.u;
        }

        float dot[EE];
#pragma unroll
        for (int e = 0; e < EE; e++) {
            float s = 0.f;
#pragma unroll
            for (int c = 0; c < 4; c++) {
                const float4 wv = *(const float4*)(Wg + e * HH + c * 256 + lane * 4);
                s += xv[c].x * wv.x + xv[c].y * wv.y + xv[c].z * wv.z + xv[c].w * wv.w;
            }
            for (int off = 32; off > 0; off >>= 1) s += __shfl_down(s, off);
            dot[e] = s;
        }
        if (lane == 0) {
            float m = dot[0];
#pragma unroll
            for (int e = 1; e < EE; e++) m = fmaxf(m, dot[e]);
            float p[EE]; float sum = 0.f;
#pragma unroll
            for (int e = 0; e < EE; e++) { p[e] = __expf(dot[e] - m); sum += p[e]; }
            const float inv = 1.f / sum;
            int i0 = 0; float v0 = p[0];
#pragma unroll
            for (int e = 1; e < EE; e++) if (p[e] > v0) { v0 = p[e]; i0 = e; }
            int i1 = -1; float v1 = -1.f;
#pragma unroll
            for (int e = 0; e < EE; e++) if (e != i0 && p[e] > v1) { v1 = p[e]; i1 = e; }
            tki[n * 2 + 0] = i0; tkv[n * 2 + 0] = v0 * inv;
            tki[n * 2 + 1] = i1; tkv[n * 2 + 1] = v1 * inv;
            atomicAdd(&hist[i0], 1);
            atomicAdd(&hist[i1], 1);
        }
    }
    __syncthreads();
    if (tid < EE) atomicAdd(&counts[tid], hist[tid]);
}

__global__ void offsets_kernel(const int* __restrict__ counts,
                               int* __restrict__ offs, int* __restrict__ cursor)
{
    if (threadIdx.x == 0 && blockIdx.x == 0) {
        int acc = 0;
        for (int e = 0; e < EE; e++) { offs[e] = acc; cursor[e] = acc; acc += counts[e]; }
    }
}

// ---------------- scatter: LDS histogram + one base atomic per expert/block ----
__global__ __launch_bounds__(256) void scatter_kernel(
    const int* __restrict__ tki, const float* __restrict__ tkv,
    int* __restrict__ cursor, int* __restrict__ stok, float* __restrict__ sval)
{
    __shared__ int hist[EE];
    __shared__ int base[EE];
    const int tid = threadIdx.x;
    const int id = blockIdx.x * 256 + tid;
    if (tid < EE) hist[tid] = 0;
    __syncthreads();
    const int e = tki[id];
    const int loc = atomicAdd(&hist[e], 1);
    __syncthreads();
    if (tid < EE) base[tid] = atomicAdd(&cursor[tid], hist[tid]);
    __syncthreads();
    const int p = base[e] + loc;
    stok[p] = id >> 1;
    sval[p] = tkv[id];
}

// ---------------- fc1: hid = silu(Xg @ W1[e]^T), bf16 out ----------------
// 128x128 tile, BK=64, XOR-swizzled LDS (chunk c of row r at c^(r&7)).
template <bool PRE>
__global__ __launch_bounds__(256) void fc1_kernel(
    const float* __restrict__ x, const ushort* __restrict__ xb,
    const float* __restrict__ W1, const ushort* __restrict__ W1b,
    const int* __restrict__ counts, const int* __restrict__ offs,
    const int* __restrict__ stok, ushort* __restrict__ hid)
{
    const int e = blockIdx.z;
    const int cnt = counts[e];
    const int row0 = blockIdx.y * 128;
    if (row0 >= cnt) return;
    const int off = offs[e];
    const int col0 = blockIdx.x * 128;

    __shared__ __align__(16) ushort As[128 * 64];
    __shared__ __align__(16) ushort Bs[128 * 64];

    const int tid = threadIdx.x;
    const int w = tid >> 6, lane = tid & 63;
    const int quad = lane >> 4, l16 = lane & 15;
    const int wm = (w >> 1) * 64, wn = (w & 1) * 64;
    const int l7 = l16 & 7;

    f32x4 acc[4][4];
#pragma unroll
    for (int mi = 0; mi < 4; mi++)
#pragma unroll
        for (int ni = 0; ni < 4; ni++) acc[mi][ni] = f32x4{0.f, 0.f, 0.f, 0.f};

    const int sub = lane >> 3;        // 0..7 row in 8-row group
    const int chk = lane & 7;         // 0..7 LDS 16B-chunk position this lane fills
    const int gchk = chk ^ sub;       // global chunk to fetch (swizzle)
    int tokA[4];
    const int fr = tid >> 1;
    const int fc = (tid & 1) * 32;
    int tokF = 0;
    if (PRE) {
#pragma unroll
        for (int i = 0; i < 4; i++) {
            int r = row0 + (w * 4 + i) * 8 + sub;
            if (r >= cnt) r = cnt - 1;
            tokA[i] = stok[off + r];
        }
    } else {
        int r = row0 + fr;
        if (r >= cnt) r = cnt - 1;
        tokF = stok[off + r];
    }

    for (int k0 = 0; k0 < HH; k0 += 64) {
        __syncthreads();
        if (PRE) {
#pragma unroll
            for (int i = 0; i < 4; i++) {
                const ushort* gA = xb + (size_t)tokA[i] * HH + k0 + gchk * 8;
                gload16(gA, &As[(w * 4 + i) * 512]);
                const ushort* gB = W1b + ((size_t)e * II + col0 + (w * 4 + i) * 8 + sub) * HH + k0 + gchk * 8;
                gload16(gB, &Bs[(w * 4 + i) * 512]);
            }
        } else {
#pragma unroll
            for (int c = 0; c < 32; c += 4) {
                const int u = fc + c;                       // ushort col 0..63
                const int sw = ((u >> 3) ^ (fr & 7)) * 8 + (u & 7);
                const float4 f = *(const float4*)(x + (size_t)tokF * HH + k0 + u);
                union { ushort h[4]; uint2 u2; } pk;
                pk.h[0] = f2bf(f.x); pk.h[1] = f2bf(f.y); pk.h[2] = f2bf(f.z); pk.h[3] = f2bf(f.w);
                *(uint2*)&As[fr * 64 + sw] = pk.u2;
                const float4 g = *(const float4*)(W1 + ((size_t)e * II + col0 + fr) * HH + k0 + u);
                pk.h[0] = f2bf(g.x); pk.h[1] = f2bf(g.y); pk.h[2] = f2bf(g.z); pk.h[3] = f2bf(g.w);
                *(uint2*)&Bs[fr * 64 + sw] = pk.u2;
            }
        }
        __syncthreads();

#pragma unroll
        for (int kk = 0; kk < 2; kk++) {
            const int pos = ((kk * 4 + quad) ^ l7) * 8;
            bf16x8 af[4], bb[4];
#pragma unroll
            for (int mi = 0; mi < 4; mi++)
                af[mi] = *(const bf16x8*)&As[(wm + mi * 16 + l16) * 64 + pos];
#pragma unroll
            for (int ni = 0; ni < 4; ni++)
                bb[ni] = *(const bf16x8*)&Bs[(wn + ni * 16 + l16) * 64 + pos];
#pragma unroll
            for (int mi = 0; mi < 4; mi++)
#pragma unroll
                for (int ni = 0; ni < 4; ni++)
                    acc[mi][ni] = __builtin_amdgcn_mfma_f32_16x16x32_bf16(af[mi], bb[ni], acc[mi][ni], 0, 0, 0);
        }
    }

    const int cnt_rem = cnt - row0;
#pragma unroll
    for (int mi = 0; mi < 4; mi++) {
#pragma unroll
        for (int j = 0; j < 4; j++) {
            const int r = wm + mi * 16 + quad * 4 + j;
            if (r < cnt_rem) {
                ushort* hrow = hid + (size_t)(off + row0 + r) * II + col0 + wn + l16;
#pragma unroll
                for (int ni = 0; ni < 4; ni++) {
                    const float v = acc[mi][ni][j];
                    const float s = v / (1.f + __expf(-v));
                    hrow[ni * 16] = f2bf(s);
                }
            }
        }
    }
}

// ---------------- fc2: out += val * (hid @ W2[e]^T) ----------------
template <bool PRE>
__global__ __launch_bounds__(256) void fc2_kernel(
    const ushort* __restrict__ hid,
    const float* __restrict__ W2, const ushort* __restrict__ W2b,
    const int* __restrict__ counts, const int* __restrict__ offs,
    const int* __restrict__ stok, const float* __restrict__ sval,
    float* __restrict__ out)
{
    const int e = blockIdx.z;
    const int cnt = counts[e];
    const int row0 = blockIdx.y * 128;
    if (row0 >= cnt) return;
    const int off = offs[e];
    const int col0 = blockIdx.x * 128;

    __shared__ __align__(16) ushort As[128 * 64];
    __shared__ __align__(16) ushort Bs[128 * 64];

    const int tid = threadIdx.x;
    const int w = tid >> 6, lane = tid & 63;
    const int quad = lane >> 4, l16 = lane & 15;
    const int wm = (w >> 1) * 64, wn = (w & 1) * 64;
    const int l7 = l16 & 7;

    f32x4 acc[4][4];
#pragma unroll
    for (int mi = 0; mi < 4; mi++)
#pragma unroll
        for (int ni = 0; ni < 4; ni++) acc[mi][ni] = f32x4{0.f, 0.f, 0.f, 0.f};

    const int sub = lane >> 3;
    const int chk = lane & 7;
    const int gchk = chk ^ sub;
    size_t slotA[4];
#pragma unroll
    for (int i = 0; i < 4; i++) {
        int s = off + row0 + (w * 4 + i) * 8 + sub;
        if (s > NPAIR - 1) s = NPAIR - 1;
        slotA[i] = (size_t)s;
    }
    const int fr = tid >> 1;
    const int fc = (tid & 1) * 32;

    for (int k0 = 0; k0 < II; k0 += 64) {
        __syncthreads();
#pragma unroll
        for (int i = 0; i < 4; i++) {
            const ushort* gA = hid + slotA[i] * II + k0 + gchk * 8;
            gload16(gA, &As[(w * 4 + i) * 512]);
        }
        if (PRE) {
#pragma unroll
            for (int i = 0; i < 4; i++) {
                const ushort* gB = W2b + ((size_t)e * HH + col0 + (w * 4 + i) * 8 + sub) * II + k0 + gchk * 8;
                gload16(gB, &Bs[(w * 4 + i) * 512]);
            }
        } else {
#pragma unroll
            for (int c = 0; c < 32; c += 4) {
                const int u = fc + c;
                const int sw = ((u >> 3) ^ (fr & 7)) * 8 + (u & 7);
                const float4 g = *(const float4*)(W2 + ((size_t)e * HH + col0 + fr) * II + k0 + u);
                union { ushort h[4]; uint2 u2; } pk;
                pk.h[0] = f2bf(g.x); pk.h[1] = f2bf(g.y); pk.h[2] = f2bf(g.z); pk.h[3] = f2bf(g.w);
                *(uint2*)&Bs[fr * 64 + sw] = pk.u2;
            }
        }
        __syncthreads();

#pragma unroll
        for (int kk = 0; kk < 2; kk++) {
            const int pos = ((kk * 4 + quad) ^ l7) * 8;
            bf16x8 af[4], bb[4];
#pragma unroll
            for (int mi = 0; mi < 4; mi++)
                af[mi] = *(const bf16x8*)&As[(wm + mi * 16 + l16) * 64 + pos];
#pragma unroll
            for (int ni = 0; ni < 4; ni++)
                bb[ni] = *(const bf16x8*)&Bs[(wn + ni * 16 + l16) * 64 + pos];
#pragma unroll
            for (int mi = 0; mi < 4; mi++)
#pragma unroll
                for (int ni = 0; ni < 4; ni++)
                    acc[mi][ni] = __builtin_amdgcn_mfma_f32_16x16x32_bf16(af[mi], bb[ni], acc[mi][ni], 0, 0, 0);
        }
    }

    const int cnt_rem = cnt - row0;
#pragma unroll
    for (int mi = 0; mi < 4; mi++) {
#pragma unroll
        for (int j = 0; j < 4; j++) {
            const int r = wm + mi * 16 + quad * 4 + j;
            if (r < cnt_rem) {
                const int p = off + row0 + r;
                const int token = stok[p];
                const float val = sval[p];
                float* orow = out + (size_t)token * HH + col0 + wn + l16;
#pragma unroll
                for (int ni = 0; ni < 4; ni++)
                    atomicAdd(&orow[ni * 16], val * acc[mi][ni][j]);
            }
        }
    }
}

extern "C" void kernel_launch(void* const* d_in, const int* in_sizes, int n_in,
                              void* d_out, int out_size, void* d_ws, size_t ws_size,
                              hipStream_t stream) {
    const float* x  = (const float*)d_in[0];
    const float* Wg = (const float*)d_in[1];
    const float* W1 = (const float*)d_in[2];
    const float* W2 = (const float*)d_in[3];
    float* out = (float*)d_out;

    char* wsb = (char*)d_ws;
    int*    counts = (int*)(wsb + 0);
    int*    cursor = (int*)(wsb + 64);
    int*    offs   = (int*)(wsb + 128);
    int*    tki    = (int*)(wsb + 256);
    float*  tkv    = (float*)(wsb + 256 + 65536);
    int*    stok   = (int*)(wsb + 256 + 2 * 65536);
    float*  sval   = (float*)(wsb + 256 + 3 * 65536);
    ushort* hid    = (ushort*)(wsb + 262400);                        // 64 MB
    ushort* W1b    = (ushort*)(wsb + 262400 + 67108864ull);          // 32 MB
    ushort* W2b    = (ushort*)(wsb + 262400 + 100663296ull);         // 32 MB
    ushort* xb     = (ushort*)(wsb + 262400 + 134217728ull);         // 16 MB
    const size_t REQ = 262400ull + 134217728ull + 16777216ull;       // ~144.3 MB
    const bool pre = ws_size >= REQ;

    hipMemsetAsync(wsb, 0, 256, stream);
    hipMemsetAsync(d_out, 0, (size_t)out_size * sizeof(float), stream);

    gate_kernel<<<NTOK / 32, 256, 0, stream>>>(x, Wg, counts, tki, tkv, xb);
    offsets_kernel<<<1, 64, 0, stream>>>(counts, offs, cursor);
    scatter_kernel<<<NPAIR / 256, 256, 0, stream>>>(tki, tkv, cursor, stok, sval);

    if (pre) {
        cvtw_kernel<<<(2 * EE * II * HH / 4) / 256, 256, 0, stream>>>(W1, W2, W1b, W2b);
        fc1_kernel<true><<<dim3(II / 128, NPAIR / 128, EE), 256, 0, stream>>>(x, xb, W1, W1b, counts, offs, stok, hid);
        fc2_kernel<true><<<dim3(HH / 128, NPAIR / 128, EE), 256, 0, stream>>>(hid, W2, W2b, counts, offs, stok, sval, out);
    } else {
        fc1_kernel<false><<<dim3(II / 128, NPAIR / 128, EE), 256, 0, stream>>>(x, xb, W1, W1b, counts, offs, stok, hid);
        fc2_kernel<false><<<dim3(HH / 128, NPAIR / 128, EE), 256, 0, stream>>>(hid, W2, W2b, counts, offs, stok, sval, out);
    }
}

// Round 5
// 455.396 us; speedup vs baseline: 1.9317x; 1.0534x over previous
//
#include <hip/hip_runtime.h>
#include <hip/hip_bf16.h>

#define HH 1024
#define II 2048
#define EE 8
#define NTOK 8192
#define NPAIR (NTOK * 2)

typedef __attribute__((ext_vector_type(8))) short bf16x8;
typedef __attribute__((ext_vector_type(4))) float f32x4;
typedef unsigned int u32;

__device__ __forceinline__ ushort f2bf(float f) {
    union { float f; unsigned u; } v; v.f = f;
    unsigned r = v.u + 0x7fffu + ((v.u >> 16) & 1u);
    return (ushort)(r >> 16);
}

__device__ __forceinline__ void gload16(const void* g, void* l) {
    __builtin_amdgcn_global_load_lds((const __attribute__((address_space(1))) u32*)g,
                                     (__attribute__((address_space(3))) u32*)l, 16, 0, 0);
}

// ---------------- fp32 -> bf16 convert for W1 and W2 (one dispatch) ----------------
__global__ __launch_bounds__(256) void cvtw_kernel(
    const float* __restrict__ W1, const float* __restrict__ W2,
    ushort* __restrict__ W1b, ushort* __restrict__ W2b)
{
    const int N1 = EE * II * HH / 4;
    const int i = blockIdx.x * 256 + threadIdx.x;
    const float4 f = (i < N1) ? ((const float4*)W1)[i] : ((const float4*)W2)[i - N1];
    union { ushort h[4]; uint2 u; } pk;
    pk.h[0] = f2bf(f.x); pk.h[1] = f2bf(f.y); pk.h[2] = f2bf(f.z); pk.h[3] = f2bf(f.w);
    if (i < N1) ((uint2*)W1b)[i] = pk.u;
    else        ((uint2*)W2b)[i - N1] = pk.u;
}

// ---------------- gate: wave-per-token + emits xb (bf16 x) ----------------
__global__ __launch_bounds__(256) void gate_kernel(
    const float* __restrict__ x, const float* __restrict__ Wg,
    int* __restrict__ counts, int* __restrict__ tki, float* __restrict__ tkv,
    ushort* __restrict__ xb)
{
    __shared__ int hist[EE];
    const int tid = threadIdx.x;
    if (tid < EE) hist[tid] = 0;
    __syncthreads();

    const int w = tid >> 6, lane = tid & 63;

#pragma unroll 1
    for (int t = 0; t < 8; t++) {
        const int n = blockIdx.x * 32 + w * 8 + t;
        const float* xr = x + (size_t)n * HH;
        float4 xv[4];
#pragma unroll
        for (int c = 0; c < 4; c++) xv[c] = *(const float4*)(xr + c * 256 + lane * 4);

#pragma unroll
        for (int c = 0; c < 4; c++) {
            union { ushort h[4]; uint2 u; } pk;
            pk.h[0] = f2bf(xv[c].x); pk.h[1] = f2bf(xv[c].y);
            pk.h[2] = f2bf(xv[c].z); pk.h[3] = f2bf(xv[c].w);
            *(uint2*)(xb + (size_t)n * HH + c * 256 + lane * 4) = pk.u;
        }

        float dot[EE];
#pragma unroll
        for (int e = 0; e < EE; e++) {
            float s = 0.f;
#pragma unroll
            for (int c = 0; c < 4; c++) {
                const float4 wv = *(const float4*)(Wg + e * HH + c * 256 + lane * 4);
                s += xv[c].x * wv.x + xv[c].y * wv.y + xv[c].z * wv.z + xv[c].w * wv.w;
            }
            for (int off = 32; off > 0; off >>= 1) s += __shfl_down(s, off);
            dot[e] = s;
        }
        if (lane == 0) {
            float m = dot[0];
#pragma unroll
            for (int e = 1; e < EE; e++) m = fmaxf(m, dot[e]);
            float p[EE]; float sum = 0.f;
#pragma unroll
            for (int e = 0; e < EE; e++) { p[e] = __expf(dot[e] - m); sum += p[e]; }
            const float inv = 1.f / sum;
            int i0 = 0; float v0 = p[0];
#pragma unroll
            for (int e = 1; e < EE; e++) if (p[e] > v0) { v0 = p[e]; i0 = e; }
            int i1 = -1; float v1 = -1.f;
#pragma unroll
            for (int e = 0; e < EE; e++) if (e != i0 && p[e] > v1) { v1 = p[e]; i1 = e; }
            tki[n * 2 + 0] = i0; tkv[n * 2 + 0] = v0 * inv;
            tki[n * 2 + 1] = i1; tkv[n * 2 + 1] = v1 * inv;
            atomicAdd(&hist[i0], 1);
            atomicAdd(&hist[i1], 1);
        }
    }
    __syncthreads();
    if (tid < EE) atomicAdd(&counts[tid], hist[tid]);
}

__global__ void offsets_kernel(const int* __restrict__ counts,
                               int* __restrict__ offs, int* __restrict__ cursor)
{
    if (threadIdx.x == 0 && blockIdx.x == 0) {
        int acc = 0;
        for (int e = 0; e < EE; e++) { offs[e] = acc; cursor[e] = acc; acc += counts[e]; }
    }
}

// ---------------- scatter: LDS histogram + one base atomic per expert/block ----
__global__ __launch_bounds__(256) void scatter_kernel(
    const int* __restrict__ tki, const float* __restrict__ tkv,
    int* __restrict__ cursor, int* __restrict__ stok, float* __restrict__ sval)
{
    __shared__ int hist[EE];
    __shared__ int base[EE];
    const int tid = threadIdx.x;
    const int id = blockIdx.x * 256 + tid;
    if (tid < EE) hist[tid] = 0;
    __syncthreads();
    const int e = tki[id];
    const int loc = atomicAdd(&hist[e], 1);
    __syncthreads();
    if (tid < EE) base[tid] = atomicAdd(&cursor[tid], hist[tid]);
    __syncthreads();
    const int p = base[e] + loc;
    stok[p] = id >> 1;
    sval[p] = tkv[id];
}

// ---------------- fc1: hid = silu(Xg @ W1[e]^T), bf16 out ----------------
// 128x128 tile, BK=64, XOR-swizzled LDS, double-buffered async staging:
// single barrier per iter; each barrier's vmcnt(0) drains loads issued one
// full compute-phase earlier.
template <bool PRE>
__global__ __launch_bounds__(256) void fc1_kernel(
    const float* __restrict__ x, const ushort* __restrict__ xb,
    const float* __restrict__ W1, const ushort* __restrict__ W1b,
    const int* __restrict__ counts, const int* __restrict__ offs,
    const int* __restrict__ stok, ushort* __restrict__ hid)
{
    const int e = blockIdx.z;
    const int cnt = counts[e];
    const int row0 = blockIdx.y * 128;
    if (row0 >= cnt) return;
    const int off = offs[e];
    const int col0 = blockIdx.x * 128;

    __shared__ __align__(16) ushort As[2][128 * 64];
    __shared__ __align__(16) ushort Bs[2][128 * 64];

    const int tid = threadIdx.x;
    const int w = tid >> 6, lane = tid & 63;
    const int quad = lane >> 4, l16 = lane & 15;
    const int wm = (w >> 1) * 64, wn = (w & 1) * 64;
    const int l7 = l16 & 7;

    f32x4 acc[4][4];
#pragma unroll
    for (int mi = 0; mi < 4; mi++)
#pragma unroll
        for (int ni = 0; ni < 4; ni++) acc[mi][ni] = f32x4{0.f, 0.f, 0.f, 0.f};

    const int sub = lane >> 3;        // 0..7 row in 8-row group
    const int chk = lane & 7;         // 0..7 LDS chunk this lane fills
    const int gchk = chk ^ sub;       // global chunk to fetch (swizzle)
    int tokA[4];
    const int fr = tid >> 1;
    const int fc = (tid & 1) * 32;
    int tokF = 0;
    if (PRE) {
#pragma unroll
        for (int i = 0; i < 4; i++) {
            int r = row0 + (w * 4 + i) * 8 + sub;
            if (r >= cnt) r = cnt - 1;
            tokA[i] = stok[off + r];
        }
    } else {
        int r = row0 + fr;
        if (r >= cnt) r = cnt - 1;
        tokF = stok[off + r];
    }

    if (PRE) {
        auto issue = [&](int buf, int k0) {
#pragma unroll
            for (int i = 0; i < 4; i++) {
                const ushort* gA = xb + (size_t)tokA[i] * HH + k0 + gchk * 8;
                gload16(gA, &As[buf][(w * 4 + i) * 512]);
                const ushort* gB = W1b + ((size_t)e * II + col0 + (w * 4 + i) * 8 + sub) * HH + k0 + gchk * 8;
                gload16(gB, &Bs[buf][(w * 4 + i) * 512]);
            }
        };
        issue(0, 0);
        const int ITERS = HH / 64;
#pragma unroll 1
        for (int it = 0; it < ITERS; it++) {
            const int cur = it & 1;
            __syncthreads();                    // drains tile-it loads (aged one iter)
            if (it + 1 < ITERS) issue(1 - cur, (it + 1) * 64);
#pragma unroll
            for (int kk = 0; kk < 2; kk++) {
                const int pos = ((kk * 4 + quad) ^ l7) * 8;
                bf16x8 af[4], bb[4];
#pragma unroll
                for (int mi = 0; mi < 4; mi++)
                    af[mi] = *(const bf16x8*)&As[cur][(wm + mi * 16 + l16) * 64 + pos];
#pragma unroll
                for (int ni = 0; ni < 4; ni++)
                    bb[ni] = *(const bf16x8*)&Bs[cur][(wn + ni * 16 + l16) * 64 + pos];
#pragma unroll
                for (int mi = 0; mi < 4; mi++)
#pragma unroll
                    for (int ni = 0; ni < 4; ni++)
                        acc[mi][ni] = __builtin_amdgcn_mfma_f32_16x16x32_bf16(af[mi], bb[ni], acc[mi][ni], 0, 0, 0);
            }
        }
    } else {
#pragma unroll 1
        for (int k0 = 0; k0 < HH; k0 += 64) {
            __syncthreads();
#pragma unroll
            for (int c = 0; c < 32; c += 4) {
                const int u = fc + c;
                const int sw = ((u >> 3) ^ (fr & 7)) * 8 + (u & 7);
                const float4 f = *(const float4*)(x + (size_t)tokF * HH + k0 + u);
                union { ushort h[4]; uint2 u2; } pk;
                pk.h[0] = f2bf(f.x); pk.h[1] = f2bf(f.y); pk.h[2] = f2bf(f.z); pk.h[3] = f2bf(f.w);
                *(uint2*)&As[0][fr * 64 + sw] = pk.u2;
                const float4 g = *(const float4*)(W1 + ((size_t)e * II + col0 + fr) * HH + k0 + u);
                pk.h[0] = f2bf(g.x); pk.h[1] = f2bf(g.y); pk.h[2] = f2bf(g.z); pk.h[3] = f2bf(g.w);
                *(uint2*)&Bs[0][fr * 64 + sw] = pk.u2;
            }
            __syncthreads();
#pragma unroll
            for (int kk = 0; kk < 2; kk++) {
                const int pos = ((kk * 4 + quad) ^ l7) * 8;
                bf16x8 af[4], bb[4];
#pragma unroll
                for (int mi = 0; mi < 4; mi++)
                    af[mi] = *(const bf16x8*)&As[0][(wm + mi * 16 + l16) * 64 + pos];
#pragma unroll
                for (int ni = 0; ni < 4; ni++)
                    bb[ni] = *(const bf16x8*)&Bs[0][(wn + ni * 16 + l16) * 64 + pos];
#pragma unroll
                for (int mi = 0; mi < 4; mi++)
#pragma unroll
                    for (int ni = 0; ni < 4; ni++)
                        acc[mi][ni] = __builtin_amdgcn_mfma_f32_16x16x32_bf16(af[mi], bb[ni], acc[mi][ni], 0, 0, 0);
            }
        }
    }

    const int cnt_rem = cnt - row0;
#pragma unroll
    for (int mi = 0; mi < 4; mi++) {
#pragma unroll
        for (int j = 0; j < 4; j++) {
            const int r = wm + mi * 16 + quad * 4 + j;
            if (r < cnt_rem) {
                ushort* hrow = hid + (size_t)(off + row0 + r) * II + col0 + wn + l16;
#pragma unroll
                for (int ni = 0; ni < 4; ni++) {
                    const float v = acc[mi][ni][j];
                    const float s = v / (1.f + __expf(-v));
                    hrow[ni * 16] = f2bf(s);
                }
            }
        }
    }
}

// ---------------- fc2: out += val * (hid @ W2[e]^T) ----------------
template <bool PRE>
__global__ __launch_bounds__(256) void fc2_kernel(
    const ushort* __restrict__ hid,
    const float* __restrict__ W2, const ushort* __restrict__ W2b,
    const int* __restrict__ counts, const int* __restrict__ offs,
    const int* __restrict__ stok, const float* __restrict__ sval,
    float* __restrict__ out)
{
    const int e = blockIdx.z;
    const int cnt = counts[e];
    const int row0 = blockIdx.y * 128;
    if (row0 >= cnt) return;
    const int off = offs[e];
    const int col0 = blockIdx.x * 128;

    __shared__ __align__(16) ushort As[2][128 * 64];
    __shared__ __align__(16) ushort Bs[2][128 * 64];

    const int tid = threadIdx.x;
    const int w = tid >> 6, lane = tid & 63;
    const int quad = lane >> 4, l16 = lane & 15;
    const int wm = (w >> 1) * 64, wn = (w & 1) * 64;
    const int l7 = l16 & 7;

    f32x4 acc[4][4];
#pragma unroll
    for (int mi = 0; mi < 4; mi++)
#pragma unroll
        for (int ni = 0; ni < 4; ni++) acc[mi][ni] = f32x4{0.f, 0.f, 0.f, 0.f};

    const int sub = lane >> 3;
    const int chk = lane & 7;
    const int gchk = chk ^ sub;
    size_t slotA[4];
#pragma unroll
    for (int i = 0; i < 4; i++) {
        int s = off + row0 + (w * 4 + i) * 8 + sub;
        if (s > NPAIR - 1) s = NPAIR - 1;
        slotA[i] = (size_t)s;
    }
    const int fr = tid >> 1;
    const int fc = (tid & 1) * 32;

    if (PRE) {
        auto issue = [&](int buf, int k0) {
#pragma unroll
            for (int i = 0; i < 4; i++) {
                const ushort* gA = hid + slotA[i] * II + k0 + gchk * 8;
                gload16(gA, &As[buf][(w * 4 + i) * 512]);
                const ushort* gB = W2b + ((size_t)e * HH + col0 + (w * 4 + i) * 8 + sub) * II + k0 + gchk * 8;
                gload16(gB, &Bs[buf][(w * 4 + i) * 512]);
            }
        };
        issue(0, 0);
        const int ITERS = II / 64;
#pragma unroll 1
        for (int it = 0; it < ITERS; it++) {
            const int cur = it & 1;
            __syncthreads();
            if (it + 1 < ITERS) issue(1 - cur, (it + 1) * 64);
#pragma unroll
            for (int kk = 0; kk < 2; kk++) {
                const int pos = ((kk * 4 + quad) ^ l7) * 8;
                bf16x8 af[4], bb[4];
#pragma unroll
                for (int mi = 0; mi < 4; mi++)
                    af[mi] = *(const bf16x8*)&As[cur][(wm + mi * 16 + l16) * 64 + pos];
#pragma unroll
                for (int ni = 0; ni < 4; ni++)
                    bb[ni] = *(const bf16x8*)&Bs[cur][(wn + ni * 16 + l16) * 64 + pos];
#pragma unroll
                for (int mi = 0; mi < 4; mi++)
#pragma unroll
                    for (int ni = 0; ni < 4; ni++)
                        acc[mi][ni] = __builtin_amdgcn_mfma_f32_16x16x32_bf16(af[mi], bb[ni], acc[mi][ni], 0, 0, 0);
            }
        }
    } else {
#pragma unroll 1
        for (int k0 = 0; k0 < II; k0 += 64) {
            __syncthreads();
#pragma unroll
            for (int i = 0; i < 4; i++) {
                const ushort* gA = hid + slotA[i] * II + k0 + gchk * 8;
                gload16(gA, &As[0][(w * 4 + i) * 512]);
            }
#pragma unroll
            for (int c = 0; c < 32; c += 4) {
                const int u = fc + c;
                const int sw = ((u >> 3) ^ (fr & 7)) * 8 + (u & 7);
                const float4 g = *(const float4*)(W2 + ((size_t)e * HH + col0 + fr) * II + k0 + u);
                union { ushort h[4]; uint2 u2; } pk;
                pk.h[0] = f2bf(g.x); pk.h[1] = f2bf(g.y); pk.h[2] = f2bf(g.z); pk.h[3] = f2bf(g.w);
                *(uint2*)&Bs[0][fr * 64 + sw] = pk.u2;
            }
            __syncthreads();
#pragma unroll
            for (int kk = 0; kk < 2; kk++) {
                const int pos = ((kk * 4 + quad) ^ l7) * 8;
                bf16x8 af[4], bb[4];
#pragma unroll
                for (int mi = 0; mi < 4; mi++)
                    af[mi] = *(const bf16x8*)&As[0][(wm + mi * 16 + l16) * 64 + pos];
#pragma unroll
                for (int ni = 0; ni < 4; ni++)
                    bb[ni] = *(const bf16x8*)&Bs[0][(wn + ni * 16 + l16) * 64 + pos];
#pragma unroll
                for (int mi = 0; mi < 4; mi++)
#pragma unroll
                    for (int ni = 0; ni < 4; ni++)
                        acc[mi][ni] = __builtin_amdgcn_mfma_f32_16x16x32_bf16(af[mi], bb[ni], acc[mi][ni], 0, 0, 0);
            }
        }
    }

    const int cnt_rem = cnt - row0;
#pragma unroll
    for (int mi = 0; mi < 4; mi++) {
#pragma unroll
        for (int j = 0; j < 4; j++) {
            const int r = wm + mi * 16 + quad * 4 + j;
            if (r < cnt_rem) {
                const int p = off + row0 + r;
                const int token = stok[p];
                const float val = sval[p];
                float* orow = out + (size_t)token * HH + col0 + wn + l16;
#pragma unroll
                for (int ni = 0; ni < 4; ni++)
                    atomicAdd(&orow[ni * 16], val * acc[mi][ni][j]);
            }
        }
    }
}

extern "C" void kernel_launch(void* const* d_in, const int* in_sizes, int n_in,
                              void* d_out, int out_size, void* d_ws, size_t ws_size,
                              hipStream_t stream) {
    const float* x  = (const float*)d_in[0];
    const float* Wg = (const float*)d_in[1];
    const float* W1 = (const float*)d_in[2];
    const float* W2 = (const float*)d_in[3];
    float* out = (float*)d_out;

    char* wsb = (char*)d_ws;
    int*    counts = (int*)(wsb + 0);
    int*    cursor = (int*)(wsb + 64);
    int*    offs   = (int*)(wsb + 128);
    int*    tki    = (int*)(wsb + 256);
    float*  tkv    = (float*)(wsb + 256 + 65536);
    int*    stok   = (int*)(wsb + 256 + 2 * 65536);
    float*  sval   = (float*)(wsb + 256 + 3 * 65536);
    ushort* hid    = (ushort*)(wsb + 262400);                        // 64 MB
    ushort* W1b    = (ushort*)(wsb + 262400 + 67108864ull);          // 32 MB
    ushort* W2b    = (ushort*)(wsb + 262400 + 100663296ull);         // 32 MB
    ushort* xb     = (ushort*)(wsb + 262400 + 134217728ull);         // 16 MB
    const size_t REQ = 262400ull + 134217728ull + 16777216ull;       // ~144.3 MB
    const bool pre = ws_size >= REQ;

    hipMemsetAsync(wsb, 0, 256, stream);
    hipMemsetAsync(d_out, 0, (size_t)out_size * sizeof(float), stream);

    gate_kernel<<<NTOK / 32, 256, 0, stream>>>(x, Wg, counts, tki, tkv, xb);
    offsets_kernel<<<1, 64, 0, stream>>>(counts, offs, cursor);
    scatter_kernel<<<NPAIR / 256, 256, 0, stream>>>(tki, tkv, cursor, stok, sval);

    if (pre) {
        cvtw_kernel<<<(2 * EE * II * HH / 4) / 256, 256, 0, stream>>>(W1, W2, W1b, W2b);
        fc1_kernel<true><<<dim3(II / 128, NPAIR / 128, EE), 256, 0, stream>>>(x, xb, W1, W1b, counts, offs, stok, hid);
        fc2_kernel<true><<<dim3(HH / 128, NPAIR / 128, EE), 256, 0, stream>>>(hid, W2, W2b, counts, offs, stok, sval, out);
    } else {
        fc1_kernel<false><<<dim3(II / 128, NPAIR / 128, EE), 256, 0, stream>>>(x, xb, W1, W1b, counts, offs, stok, hid);
        fc2_kernel<false><<<dim3(HH / 128, NPAIR / 128, EE), 256, 0, stream>>>(hid, W2, W2b, counts, offs, stok, sval, out);
    }
}